// Round 1
// baseline (111.108 us; speedup 1.0000x reference)
//
#include <hip/hip_runtime.h>

// Problem constants (reference: N=16384, K=32, D=256)
#define N_ 16384
#define K_ 32
#define D_ 256
#define NEG_SLOPE 0.01f

// ---------------------------------------------------------------------------
// Prologue: v[e] = sum_d a_w[d] * W[d,e]   (a_w @ W, D floats)
//           ws[D] = 2*dot(b, a_w) + a_b    (scalar bias folded into score)
// One block, 1024 threads: thread (dd,e) handles 64 d's for column e.
// ---------------------------------------------------------------------------
__global__ __launch_bounds__(1024) void prep_kernel(
    const float* __restrict__ W, const float* __restrict__ b,
    const float* __restrict__ a_w, const float* __restrict__ a_b,
    float* __restrict__ ws) {
  __shared__ float part[4][D_];
  const int t = threadIdx.x;
  const int dd = t >> 8;   // 0..3
  const int e = t & 255;
  float acc = 0.f;
#pragma unroll 8
  for (int j = 0; j < 64; ++j) {
    const int d = dd * 64 + j;
    acc += a_w[d] * W[d * D_ + e];
  }
  part[dd][e] = acc;
  __syncthreads();
  if (t < D_) ws[t] = part[0][t] + part[1][t] + part[2][t] + part[3][t];
  __syncthreads();
  if (t < D_) part[0][t] = b[t] * a_w[t];
  __syncthreads();
  if (t == 0) {
    float s = 0.f;
    for (int i = 0; i < D_; ++i) s += part[0][i];
    ws[D_] = 2.f * s + a_b[0];
  }
}

// ---------------------------------------------------------------------------
// Main: one block per n. Stage middle[n] (32KB) in LDS once, fusing the
// dot-with-v into the load. Softmax over K in wave 0. Weighted sum from LDS.
// LDS float4 slots XOR-swizzled by row (p = s ^ (r&7)) for conflict-free
// b128 writes and scalar reads (row stride 256 floats is 0 mod 32 banks).
// ---------------------------------------------------------------------------
__global__ __launch_bounds__(256) void attn_agg_kernel(
    const float* __restrict__ target, const float* __restrict__ middle,
    const float* __restrict__ ws, float* __restrict__ out) {
  __shared__ __align__(16) float smid[K_ * D_];  // 32 KB, swizzled
  __shared__ __align__(16) float lv[D_];
  __shared__ float sdot[K_];
  __shared__ float stp[4];
  __shared__ float scoef[K_];

  const int n = blockIdx.x;
  const int t = threadIdx.x;
  const int r = t >> 3;  // row k this thread helps load, 0..31
  const int c = t & 7;   // lane-in-row, 0..7

  lv[t] = ws[t];
  __syncthreads();

  const float4* mrow = (const float4*)(middle + (size_t)n * K_ * D_);
  // Thread covers row r, logical float4 slots s = c + 8*i (i = 0..7).
  // Global: for fixed i a wave touches 8 aligned 128B segments — coalesced.
  float pdot = 0.f;
#pragma unroll
  for (int i = 0; i < 8; ++i) {
    const int s = c + i * 8;              // logical slot in row, 0..63
    const float4 m4 = mrow[r * 64 + s];
    const float4 v4 = *(const float4*)(lv + s * 4);
    pdot += m4.x * v4.x + m4.y * v4.y + m4.z * v4.z + m4.w * v4.w;
    const int p = s ^ (r & 7);            // swizzled physical slot
    *(float4*)(smid + r * D_ + p * 4) = m4;
  }
  // Reduce pdot across the 8 lanes of this row (consecutive lanes, same wave)
  pdot += __shfl_xor(pdot, 1);
  pdot += __shfl_xor(pdot, 2);
  pdot += __shfl_xor(pdot, 4);
  if (c == 0) sdot[r] = pdot;

  // tdot = target[n] . v  (block-wide reduction over 256 lanes)
  float tp = target[(size_t)n * D_ + t] * lv[t];
#pragma unroll
  for (int off = 1; off < 64; off <<= 1) tp += __shfl_xor(tp, off);
  if ((t & 63) == 0) stp[t >> 6] = tp;
  __syncthreads();

  // Softmax over K=32 in wave 0 (both 32-lane halves compute duplicates)
  if (t < 64) {
    const float tdot = stp[0] + stp[1] + stp[2] + stp[3];
    const float cadd = ws[D_];
    const int k = t & 31;
    float sc = sdot[k] + tdot + cadd;
    sc = sc > 0.f ? sc : NEG_SLOPE * sc;  // leaky_relu
    float mx = sc;
    mx = fmaxf(mx, __shfl_xor(mx, 1));
    mx = fmaxf(mx, __shfl_xor(mx, 2));
    mx = fmaxf(mx, __shfl_xor(mx, 4));
    mx = fmaxf(mx, __shfl_xor(mx, 8));
    mx = fmaxf(mx, __shfl_xor(mx, 16));
    float ex = __expf(sc - mx);
    float sum = ex;
    sum += __shfl_xor(sum, 1);
    sum += __shfl_xor(sum, 2);
    sum += __shfl_xor(sum, 4);
    sum += __shfl_xor(sum, 8);
    sum += __shfl_xor(sum, 16);
    if (t < 32) scoef[k] = ex / sum;
  }
  __syncthreads();

  // Pass 2: out[n, t] = sum_k coef[k] * middle[n, k, t]
  float acc = 0.f;
  const int s2 = t >> 2;   // logical float4 slot of column t
  const int e2 = t & 3;    // element within the float4
#pragma unroll
  for (int k = 0; k < K_; ++k) {
    const int p = s2 ^ (k & 7);
    acc += scoef[k] * smid[k * D_ + p * 4 + e2];
  }
  out[(size_t)n * D_ + t] = acc;
}

extern "C" void kernel_launch(void* const* d_in, const int* in_sizes, int n_in,
                              void* d_out, int out_size, void* d_ws, size_t ws_size,
                              hipStream_t stream) {
  const float* target = (const float*)d_in[0];
  const float* middle = (const float*)d_in[1];
  const float* W      = (const float*)d_in[2];
  const float* b      = (const float*)d_in[3];
  const float* a_w    = (const float*)d_in[4];
  const float* a_b    = (const float*)d_in[5];
  float* out = (float*)d_out;
  float* ws  = (float*)d_ws;  // needs (D_+1) floats

  prep_kernel<<<1, 1024, 0, stream>>>(W, b, a_w, a_b, ws);
  attn_agg_kernel<<<N_, 256, 0, stream>>>(target, middle, ws, out);
}